// Round 6
// baseline (616.755 us; speedup 1.0000x reference)
//
#include <hip/hip_runtime.h>
#include <stdint.h>

#define T_SEQ 4096
#define HID   2048
#define NH    16
#define HD    128

typedef __attribute__((ext_vector_type(8))) short short8;
typedef __attribute__((ext_vector_type(4))) short short4v;
typedef __attribute__((ext_vector_type(4))) float f32x4;

typedef __attribute__((address_space(1))) void as1_void;
typedef __attribute__((address_space(3))) void as3_void;

__device__ __forceinline__ unsigned short f2bf(float f){
  unsigned u = __builtin_bit_cast(unsigned, f);
  u += 0x7fffu + ((u >> 16) & 1u);
  return (unsigned short)(u >> 16);
}
__device__ __forceinline__ float bf2f(unsigned short b){
  unsigned u = ((unsigned)b) << 16;
  return __builtin_bit_cast(float, u);
}
// async global->LDS, 16B per lane. LDS side is wave-uniform base + lane*16.
__device__ __forceinline__ void gll16(const void* g, void* l){
  __builtin_amdgcn_global_load_lds((as1_void*)(uintptr_t)g,
                                   (as3_void*)(unsigned)(uintptr_t)l, 16, 0, 0);
}

// ---------------- fp32 -> bf16 conversion of X ----------------
__global__ __launch_bounds__(256) void conv_x_k(const float* __restrict__ X,
                                                unsigned short* __restrict__ O){
  int i = (blockIdx.x * 256 + threadIdx.x) * 4;
  float4 v = *(const float4*)(X + i);
  short4v o;
  o[0] = (short)f2bf(v.x); o[1] = (short)f2bf(v.y);
  o[2] = (short)f2bf(v.z); o[3] = (short)f2bf(v.w);
  *(short4v*)(O + i) = o;
}

// ------------- weight transpose + bf16: W[k][n] -> Wt[n][k] -------------
__global__ __launch_bounds__(256) void conv_wt_k(const float* __restrict__ W0,
                                                 const float* __restrict__ W1,
                                                 const float* __restrict__ W2,
                                                 const float* __restrict__ W3,
                                                 unsigned short* __restrict__ Wt){
  const float* W = (blockIdx.z == 0) ? W0 : (blockIdx.z == 1) ? W1
                   : (blockIdx.z == 2) ? W2 : W3;
  unsigned short* out = Wt + (size_t)blockIdx.z * HID * HID;
  __shared__ float tile[32][33];
  const int x = threadIdx.x;       // 0..31
  const int y = threadIdx.y;       // 0..7
  const int k0 = blockIdx.y * 32, n0 = blockIdx.x * 32;
#pragma unroll
  for (int i = 0; i < 4; ++i){
    int r = y * 4 + i;
    tile[r][x] = W[(size_t)(k0 + r) * HID + n0 + x];
  }
  __syncthreads();
#pragma unroll
  for (int i = 0; i < 4; ++i){
    int r = y * 4 + i;
    out[(size_t)(n0 + r) * HID + k0 + x] = f2bf(tile[x][r]);
  }
}

// ---------------- GEMM: C[M][N] = A[M][K=2048] * Bt[N][K]^T ----------------
// 128x128 tile, 4 waves (2x2), BK=64, global_load_lds(16B). LDS slot (row,c)
// holds global chunk c ^ (row&7); fragment read chunk (ks*4+qd) ^ (mm&7).
template<int MODE, int NTOT>
__global__ __launch_bounds__(256, 3) void gemm_bt(
    const unsigned short* __restrict__ A,
    const unsigned short* __restrict__ Bt,
    unsigned short* __restrict__ Qb,
    unsigned short* __restrict__ Kb,
    unsigned short* __restrict__ Vt,
    float* __restrict__ Cf)
{
  constexpr int K = HID;
  __shared__ __align__(16) unsigned short lA[128 * 64];
  __shared__ __align__(16) unsigned short lB[128 * 64];

  const int tid  = threadIdx.x;
  const int wave = tid >> 6;
  const int lane = tid & 63;
  const int qd   = lane >> 4;
  const int mm   = lane & 15;
  const int m7   = mm & 7;
  const int wm   = wave >> 1;
  const int wn   = wave & 1;
  const int bm   = blockIdx.y * 128;
  const int bn   = blockIdx.x * 128;

  const unsigned short* ga[4];
  const unsigned short* gb[4];
  unsigned short* la[4];
  unsigned short* lbp[4];
#pragma unroll
  for (int i = 0; i < 4; ++i){
    int s0   = (wave * 4 + i) * 64;   // wave-uniform base slot
    int slot = s0 + lane;
    int row  = slot >> 3;
    int kb   = (slot & 7) ^ (row & 7);
    ga[i]  = A  + (size_t)(bm + row) * K + kb * 8;
    gb[i]  = Bt + (size_t)(bn + row) * K + kb * 8;
    la[i]  = lA + s0 * 8;
    lbp[i] = lB + s0 * 8;
  }

  int abase[4], bbase[4];
#pragma unroll
  for (int t = 0; t < 4; ++t){
    abase[t] = (wm * 64 + t * 16 + mm) * 8;
    bbase[t] = (wn * 64 + t * 16 + mm) * 8;
  }

  const f32x4 fzero = {0.f, 0.f, 0.f, 0.f};
  f32x4 acc[4][4];
#pragma unroll
  for (int i = 0; i < 4; ++i)
#pragma unroll
    for (int j = 0; j < 4; ++j) acc[i][j] = fzero;

  for (int k0 = 0; k0 < K; k0 += 64){
    __syncthreads();
#pragma unroll
    for (int i = 0; i < 4; ++i){
      gll16(ga[i] + k0, la[i]);
      gll16(gb[i] + k0, lbp[i]);
    }
    __syncthreads();
#pragma unroll
    for (int ks = 0; ks < 2; ++ks){
      const int co = (ks * 4 + qd) ^ m7;
      short8 af[4], bfv[4];
#pragma unroll
      for (int t = 0; t < 4; ++t) af[t]  = *(const short8*)(lA + (abase[t] + co) * 8);
#pragma unroll
      for (int t = 0; t < 4; ++t) bfv[t] = *(const short8*)(lB + (bbase[t] + co) * 8);
#pragma unroll
      for (int i = 0; i < 4; ++i)
#pragma unroll
        for (int j = 0; j < 4; ++j)
          acc[i][j] = __builtin_amdgcn_mfma_f32_16x16x32_bf16(af[i], bfv[j], acc[i][j], 0, 0, 0);
    }
  }

#pragma unroll
  for (int i = 0; i < 4; ++i){
#pragma unroll
    for (int j = 0; j < 4; ++j){
      const int col = bn + wn * 64 + j * 16 + mm;
#pragma unroll
      for (int r = 0; r < 4; ++r){
        const int row = bm + wm * 64 + i * 16 + qd * 4 + r;
        const float v = acc[i][j][r];
        if (MODE == 0){
          const int sel = col >> 11;
          const int nn  = col & 2047;
          const int h   = nn >> 7;
          const int d   = nn & 127;
          const unsigned short bv = f2bf(v);
          if (sel == 0)      Qb[((size_t)h * T_SEQ + row) * HD + d] = bv;
          else if (sel == 1) Kb[((size_t)h * T_SEQ + row) * HD + d] = bv;
          else               Vt[((size_t)(h * HD + d)) * T_SEQ + row] = bv;
        } else {
          Cf[(size_t)row * NTOT + col] = v;
        }
      }
    }
  }
}

// ---------------- RoPE on Q and K (in place, bf16) ----------------
__global__ __launch_bounds__(256) void rope_k(unsigned short* __restrict__ Qb,
                                              unsigned short* __restrict__ Kb){
  const int j = threadIdx.x & 63;
  const int t = blockIdx.x * 4 + (threadIdx.x >> 6);
  const int h = blockIdx.y;
  const float fr = (float)t * __expf(-(float)j * (9.210340371976184f / 64.f));
  const float cs = cosf(fr), sn = sinf(fr);
  const size_t base = ((size_t)h * T_SEQ + t) * HD;
  {
    float x1 = bf2f(Qb[base + j]), x2 = bf2f(Qb[base + j + 64]);
    Qb[base + j]      = f2bf(x1 * cs - x2 * sn);
    Qb[base + j + 64] = f2bf(x2 * cs + x1 * sn);
  }
  {
    float x1 = bf2f(Kb[base + j]), x2 = bf2f(Kb[base + j + 64]);
    Kb[base + j]      = f2bf(x1 * cs - x2 * sn);
    Kb[base + j + 64] = f2bf(x2 * cs + x1 * sn);
  }
}

// ---------------- flash attention v6 ----------------
// Block = 4 waves = 2 row-groups (rg, 32 q-rows) x 2 key-groups (kg, 32 keys).
// ONE 64-row q-tile per block; grid = 1024 (16 heads x 64 tiles), tiles
// issued LONGEST-FIRST (LPT) so 4-deep residency backfills the imbalance.
// (v5's 512 balanced-pair grid capped residency at 2 blocks/CU - the grid,
// not LDS, was the occupancy limit.)
// LDS = exactly 32768 B (lK 16K + lV 16K): P round-trips through the lK
// region, which is dead after the kf reads; a 3rd barrier per iter orders
// kf-read -> P-write. 163840/32768 = 5 blocks by LDS; VGPR(<=128 via
// __launch_bounds__(256,4)) gives 4 blocks/CU = 4 waves/SIMD.
// P stride = 36 shorts: write banks (8*qd + cc>>1 + C)%32 = all 32 distinct
// -> conflict-free (v5's stride-32 was 8-way = 9.7M conflict cycles).
// Softcap poly (1 transcendental), clamp via v_med3; fixed-max softmax.
__global__ __launch_bounds__(256, 4) void attn_k(
    const unsigned short* __restrict__ Qb,   // [NH][T][HD]
    const unsigned short* __restrict__ Kb,   // [NH][T][HD]
    const unsigned short* __restrict__ Vt,   // [NH][HD][T]
    unsigned short* __restrict__ Yb)         // [T][HID]
{
  __shared__ __align__(16) unsigned char smem[32768];
  unsigned short* lK = (unsigned short*)smem;              // [64 keys][128 d] 16 KB
  unsigned short* lV = (unsigned short*)(smem + 16384);    // [128 d][64 keys] 16 KB
  float* lL = (float*)smem;                                // [64] (epilogue phase A)
  float* lO = (float*)smem;                                // [128][64] (epilogue phase C)

  const int tid  = threadIdx.x;
  const int w    = tid >> 6;
  const int rg   = w >> 1;
  const int kg   = w & 1;
  const int lane = tid & 63;
  const int qd   = lane >> 4;
  const int cc   = lane & 15;
  const int cx   = cc & 7;
  const int r8   = lane >> 3, c7 = lane & 7;

  const int b = blockIdx.x;                    // 1024 blocks
  const int h = (b & 7) + 8 * ((b >> 3) & 1);  // head; b&7 -> XCD pin
  const int tp = 63 - (b >> 4);                // tile, longest first (LPT)

  // staging source addressing (swizzle on fetch side; slot chunk c holds
  // global chunk c ^ (row&7))
  const int ce  = cc ^ qd;
  const int dlt = (ce & 4) ? -32 : 32;
  const unsigned short* gKbp = Kb + ((size_t)h * T_SEQ + w * 16 + qd) * HD + ce * 8;
  const int cV = c7 ^ r8;
  const unsigned short* gVbp = Vt + ((size_t)h * HD + w * 32 + r8) * T_SEQ + cV * 8;

  // per-wave P slice inside lK region: 4 KB each, stride 36 shorts
  unsigned short* lPw = lK + w * 2048;

  const f32x4 fzero = {0.f, 0.f, 0.f, 0.f};
  // 50*tanh(s*SCALE/50) ~= s*(A0 + A1*s^2 + A2*s^4)
  const float A0 = 0.0625f;
  const float A1 = -3.2552083e-8f;
  const float A2 = 2.0345052e-14f;

  const int qrow0 = tp * 64 + rg * 32;
  const int iters = tp + 1;

  // Q fragments: A-layout, rows qrow0 + mt*16 + cc, d = ks*32 + qd*8
  short8 qf[2][4];
#pragma unroll
  for (int mt = 0; mt < 2; ++mt)
#pragma unroll
    for (int ks = 0; ks < 4; ++ks)
      qf[mt][ks] = *(const short8*)(Qb + ((size_t)h * T_SEQ + qrow0 + mt * 16 + cc) * HD + ks * 32 + qd * 8);

  f32x4 o[2][8];
  float lsum[2][4];
#pragma unroll
  for (int mt = 0; mt < 2; ++mt){
#pragma unroll
    for (int dn = 0; dn < 8; ++dn) o[mt][dn] = fzero;
#pragma unroll
    for (int r = 0; r < 4; ++r) lsum[mt][r] = 0.f;
  }

#pragma unroll 1
  for (int it = 0; it < iters; ++it){
    const int k0 = it * 64;
    __syncthreads();   // B_a: prev iter's lK(P)/lV reads done
    {
      const unsigned short* gK = gKbp + (size_t)k0 * HD;
      const unsigned short* gV = gVbp + k0;
      unsigned short* dK = lK + w * 2048;
      unsigned short* dV = lV + w * 2048;
#pragma unroll
      for (int i = 0; i < 4; ++i)
        gll16(gK + (size_t)(i * 4) * HD + ((i & 1) ? dlt : 0), dK + i * 512);
#pragma unroll
      for (int i = 0; i < 4; ++i)
        gll16(gV + (size_t)i * 8 * T_SEQ, dV + i * 512);
    }
    __syncthreads();   // B_b: tiles visible

    // S = Q K^T : wave's keys = k0 + kg*32 + nt*16 + cc (nt=0..1)
    f32x4 S[2][2];
#pragma unroll
    for (int mt = 0; mt < 2; ++mt)
#pragma unroll
      for (int nt = 0; nt < 2; ++nt) S[mt][nt] = fzero;
#pragma unroll
    for (int nt = 0; nt < 2; ++nt){
      short8 kf[4];
#pragma unroll
      for (int ks = 0; ks < 4; ++ks)
        kf[ks] = *(const short8*)(lK + ((kg * 32 + nt * 16 + cc) * 16 + ((ks * 4 + qd) ^ cx)) * 8);
#pragma unroll
      for (int mt = 0; mt < 2; ++mt)
#pragma unroll
        for (int ks = 0; ks < 4; ++ks)
          S[mt][nt] = __builtin_amdgcn_mfma_f32_16x16x32_bf16(qf[mt][ks], kf[ks], S[mt][nt], 0, 0, 0);
    }

    // softcap (poly + med3 clamp) + exp, results in regs
    const bool domask = (it == iters - 1);
    unsigned short pv[2][2][4];
#pragma unroll
    for (int mt = 0; mt < 2; ++mt)
#pragma unroll
      for (int nt = 0; nt < 2; ++nt)
#pragma unroll
        for (int r = 0; r < 4; ++r){
          float s = S[mt][nt][r];
          float w2 = s * s;
          float t = fmaf(w2, A2, A1);
          t = fmaf(w2, t, A0);
          float a = __builtin_amdgcn_fmed3f(s * t, -50.f, 50.f);
          float p = __expf(a);
          if (domask){
            int col = k0 + kg * 32 + nt * 16 + cc;
            int row = qrow0 + mt * 16 + qd * 4 + r;
            if (col > row) p = 0.f;
          }
          unsigned u = __builtin_bit_cast(unsigned, p);
          lsum[mt][r] += __builtin_bit_cast(float, u & 0xffff0000u);
          pv[mt][nt][r] = (unsigned short)(u >> 16);
        }

    __syncthreads();   // B_c: all waves' kf reads done -> lK(P region) free

    // P write: stride 36 -> banks (8qd + cc>>1)%32, conflict-free
#pragma unroll
    for (int mt = 0; mt < 2; ++mt)
#pragma unroll
      for (int nt = 0; nt < 2; ++nt)
#pragma unroll
        for (int r = 0; r < 4; ++r)
          lPw[(mt * 16 + qd * 4 + r) * 36 + nt * 16 + cc] = pv[mt][nt][r];

    // P fragments (A-layout): row = mt*16+cc, keys qd*8..+7 (2x b64, 8B-aligned)
    short8 pf[2];
#pragma unroll
    for (int mt = 0; mt < 2; ++mt){
      const unsigned short* pb = lPw + (mt * 16 + cc) * 36 + qd * 8;
      union { short8 v; short4v hh[2]; } u;
      u.hh[0] = *(const short4v*)pb;
      u.hh[1] = *(const short4v*)(pb + 4);
      pf[mt] = u.v;
    }

    // O += P V : B-frag from lV, d-row = dn*16+cc, key chunk = kg*4+qd
#pragma unroll
    for (int dn = 0; dn < 8; ++dn){
      short8 vf = *(const short8*)(lV + ((dn * 16 + cc) * 8 + ((kg * 4 + qd) ^ cx)) * 8);
#pragma unroll
      for (int mt = 0; mt < 2; ++mt)
        o[mt][dn] = __builtin_amdgcn_mfma_f32_16x16x32_bf16(pf[mt], vf, o[mt][dn], 0, 0, 0);
    }
  }

  // ---- epilogue: reduce l over cc, merge kg partials (additive), store ----
  float lred[2][4];
#pragma unroll
  for (int mt = 0; mt < 2; ++mt)
#pragma unroll
    for (int r = 0; r < 4; ++r){
      float lb = lsum[mt][r];
      lb += __shfl_xor(lb, 1);
      lb += __shfl_xor(lb, 2);
      lb += __shfl_xor(lb, 4);
      lb += __shfl_xor(lb, 8);
      lred[mt][r] = lb;
    }

  __syncthreads();   // all K/V/P reads done; smem reusable
  // phase A: kg==1 publishes its l
  if (kg == 1 && cc == 0){
#pragma unroll
    for (int mt = 0; mt < 2; ++mt)
#pragma unroll
      for (int r = 0; r < 4; ++r)
        lL[rg * 32 + mt * 16 + qd * 4 + r] = lred[mt][r];
  }
  __syncthreads();
  // phase B: kg==0 computes inv from merged l
  float inv[2][4];
  if (kg == 0){
#pragma unroll
    for (int mt = 0; mt < 2; ++mt)
#pragma unroll
      for (int r = 0; r < 4; ++r)
        inv[mt][r] = __builtin_amdgcn_rcpf(lred[mt][r] + lL[rg * 32 + mt * 16 + qd * 4 + r]);
  }
  __syncthreads();
  // phase C: kg==1 publishes its O partial [128 d][64 rows]
  if (kg == 1){
#pragma unroll
    for (int mt = 0; mt < 2; ++mt)
#pragma unroll
      for (int dn = 0; dn < 8; ++dn)
        *(f32x4*)&lO[(dn * 16 + cc) * 64 + rg * 32 + mt * 16 + qd * 4] = o[mt][dn];
  }
  __syncthreads();
  // phase D: kg==0 merges, normalizes, stores
  if (kg == 0){
#pragma unroll
    for (int mt = 0; mt < 2; ++mt){
#pragma unroll
      for (int dn = 0; dn < 8; ++dn){
        f32x4 oo = o[mt][dn] + *(const f32x4*)&lO[(dn * 16 + cc) * 64 + rg * 32 + mt * 16 + qd * 4];
#pragma unroll
        for (int r = 0; r < 4; ++r){
          int row = qrow0 + mt * 16 + qd * 4 + r;
          Yb[(size_t)row * HID + h * HD + dn * 16 + cc] = f2bf(oo[r] * inv[mt][r]);
        }
      }
    }
  }
}

extern "C" void kernel_launch(void* const* d_in, const int* in_sizes, int n_in,
                              void* d_out, int out_size, void* d_ws, size_t ws_size,
                              hipStream_t stream) {
  const float* X  = (const float*)d_in[0];
  const float* Wq = (const float*)d_in[1];
  const float* Wk = (const float*)d_in[2];
  const float* Wv = (const float*)d_in[3];
  const float* Wo = (const float*)d_in[4];
  float* out = (float*)d_out;

  unsigned short* ws = (unsigned short*)d_ws;
  unsigned short* Xb = ws;                                   // [T][HID]        16 MiB
  unsigned short* Wt = ws + (size_t)8  * 1024 * 1024;        // [4*2048][2048]  32 MiB
  unsigned short* Qb = ws + (size_t)24 * 1024 * 1024;        // [NH][T][HD]     16 MiB
  unsigned short* Kb = ws + (size_t)32 * 1024 * 1024;        // [NH][T][HD]     16 MiB
  unsigned short* Vt = ws + (size_t)40 * 1024 * 1024;        // [NH][HD][T]     16 MiB
  unsigned short* Yb = Xb;                                   // reuse X region

  conv_x_k<<<8192, 256, 0, stream>>>(X, Xb);
  conv_wt_k<<<dim3(64, 64, 4), dim3(32, 8), 0, stream>>>(Wq, Wk, Wv, Wo, Wt);
  gemm_bt<0, 6144><<<dim3(48, 32), 256, 0, stream>>>(Xb, Wt, Qb, Kb, Vt, nullptr);
  rope_k<<<dim3(1024, NH), 256, 0, stream>>>(Qb, Kb);
  attn_k<<<dim3(1024), 256, 0, stream>>>(Qb, Kb, Vt, Yb);
  gemm_bt<1, 2048><<<dim3(16, 32), 256, 0, stream>>>(Yb, Wt + (size_t)6144 * 2048,
                                                     nullptr, nullptr, nullptr, out);
}

// Round 7
// 456.512 us; speedup vs baseline: 1.3510x; 1.3510x over previous
//
#include <hip/hip_runtime.h>
#include <stdint.h>

#define T_SEQ 4096
#define HID   2048
#define NH    16
#define HD    128

typedef __attribute__((ext_vector_type(8))) short short8;
typedef __attribute__((ext_vector_type(4))) short short4v;
typedef __attribute__((ext_vector_type(4))) float f32x4;

typedef __attribute__((address_space(1))) void as1_void;
typedef __attribute__((address_space(3))) void as3_void;

__device__ __forceinline__ unsigned short f2bf(float f){
  unsigned u = __builtin_bit_cast(unsigned, f);
  u += 0x7fffu + ((u >> 16) & 1u);
  return (unsigned short)(u >> 16);
}
__device__ __forceinline__ float bf2f(unsigned short b){
  unsigned u = ((unsigned)b) << 16;
  return __builtin_bit_cast(float, u);
}
// async global->LDS, 16B per lane. LDS side is wave-uniform base + lane*16.
__device__ __forceinline__ void gll16(const void* g, void* l){
  __builtin_amdgcn_global_load_lds((as1_void*)(uintptr_t)g,
                                   (as3_void*)(unsigned)(uintptr_t)l, 16, 0, 0);
}

// ---------------- fp32 -> bf16 conversion of X ----------------
__global__ __launch_bounds__(256) void conv_x_k(const float* __restrict__ X,
                                                unsigned short* __restrict__ O){
  int i = (blockIdx.x * 256 + threadIdx.x) * 4;
  float4 v = *(const float4*)(X + i);
  short4v o;
  o[0] = (short)f2bf(v.x); o[1] = (short)f2bf(v.y);
  o[2] = (short)f2bf(v.z); o[3] = (short)f2bf(v.w);
  *(short4v*)(O + i) = o;
}

// ------------- weight transpose + bf16: W[k][n] -> Wt[n][k] -------------
__global__ __launch_bounds__(256) void conv_wt_k(const float* __restrict__ W0,
                                                 const float* __restrict__ W1,
                                                 const float* __restrict__ W2,
                                                 const float* __restrict__ W3,
                                                 unsigned short* __restrict__ Wt){
  const float* W = (blockIdx.z == 0) ? W0 : (blockIdx.z == 1) ? W1
                   : (blockIdx.z == 2) ? W2 : W3;
  unsigned short* out = Wt + (size_t)blockIdx.z * HID * HID;
  __shared__ float tile[32][33];
  const int x = threadIdx.x;       // 0..31
  const int y = threadIdx.y;       // 0..7
  const int k0 = blockIdx.y * 32, n0 = blockIdx.x * 32;
#pragma unroll
  for (int i = 0; i < 4; ++i){
    int r = y * 4 + i;
    tile[r][x] = W[(size_t)(k0 + r) * HID + n0 + x];
  }
  __syncthreads();
#pragma unroll
  for (int i = 0; i < 4; ++i){
    int r = y * 4 + i;
    out[(size_t)(n0 + r) * HID + k0 + x] = f2bf(tile[x][r]);
  }
}

// ---------------- GEMM: C[M][N] = A[M][K=2048] * Bt[N][K]^T ----------------
// 128x128 tile, 4 waves (2x2), BK=64, global_load_lds(16B). LDS slot (row,c)
// holds global chunk c ^ (row&7); fragment read chunk (ks*4+qd) ^ (mm&7).
template<int MODE, int NTOT>
__global__ __launch_bounds__(256, 3) void gemm_bt(
    const unsigned short* __restrict__ A,
    const unsigned short* __restrict__ Bt,
    unsigned short* __restrict__ Qb,
    unsigned short* __restrict__ Kb,
    unsigned short* __restrict__ Vt,
    float* __restrict__ Cf)
{
  constexpr int K = HID;
  __shared__ __align__(16) unsigned short lA[128 * 64];
  __shared__ __align__(16) unsigned short lB[128 * 64];

  const int tid  = threadIdx.x;
  const int wave = tid >> 6;
  const int lane = tid & 63;
  const int qd   = lane >> 4;
  const int mm   = lane & 15;
  const int m7   = mm & 7;
  const int wm   = wave >> 1;
  const int wn   = wave & 1;
  const int bm   = blockIdx.y * 128;
  const int bn   = blockIdx.x * 128;

  const unsigned short* ga[4];
  const unsigned short* gb[4];
  unsigned short* la[4];
  unsigned short* lbp[4];
#pragma unroll
  for (int i = 0; i < 4; ++i){
    int s0   = (wave * 4 + i) * 64;   // wave-uniform base slot
    int slot = s0 + lane;
    int row  = slot >> 3;
    int kb   = (slot & 7) ^ (row & 7);
    ga[i]  = A  + (size_t)(bm + row) * K + kb * 8;
    gb[i]  = Bt + (size_t)(bn + row) * K + kb * 8;
    la[i]  = lA + s0 * 8;
    lbp[i] = lB + s0 * 8;
  }

  int abase[4], bbase[4];
#pragma unroll
  for (int t = 0; t < 4; ++t){
    abase[t] = (wm * 64 + t * 16 + mm) * 8;
    bbase[t] = (wn * 64 + t * 16 + mm) * 8;
  }

  const f32x4 fzero = {0.f, 0.f, 0.f, 0.f};
  f32x4 acc[4][4];
#pragma unroll
  for (int i = 0; i < 4; ++i)
#pragma unroll
    for (int j = 0; j < 4; ++j) acc[i][j] = fzero;

  for (int k0 = 0; k0 < K; k0 += 64){
    __syncthreads();
#pragma unroll
    for (int i = 0; i < 4; ++i){
      gll16(ga[i] + k0, la[i]);
      gll16(gb[i] + k0, lbp[i]);
    }
    __syncthreads();
#pragma unroll
    for (int ks = 0; ks < 2; ++ks){
      const int co = (ks * 4 + qd) ^ m7;
      short8 af[4], bfv[4];
#pragma unroll
      for (int t = 0; t < 4; ++t) af[t]  = *(const short8*)(lA + (abase[t] + co) * 8);
#pragma unroll
      for (int t = 0; t < 4; ++t) bfv[t] = *(const short8*)(lB + (bbase[t] + co) * 8);
#pragma unroll
      for (int i = 0; i < 4; ++i)
#pragma unroll
        for (int j = 0; j < 4; ++j)
          acc[i][j] = __builtin_amdgcn_mfma_f32_16x16x32_bf16(af[i], bfv[j], acc[i][j], 0, 0, 0);
    }
  }

#pragma unroll
  for (int i = 0; i < 4; ++i){
#pragma unroll
    for (int j = 0; j < 4; ++j){
      const int col = bn + wn * 64 + j * 16 + mm;
#pragma unroll
      for (int r = 0; r < 4; ++r){
        const int row = bm + wm * 64 + i * 16 + qd * 4 + r;
        const float v = acc[i][j][r];
        if (MODE == 0){
          const int sel = col >> 11;
          const int nn  = col & 2047;
          const int h   = nn >> 7;
          const int d   = nn & 127;
          const unsigned short bv = f2bf(v);
          if (sel == 0)      Qb[((size_t)h * T_SEQ + row) * HD + d] = bv;
          else if (sel == 1) Kb[((size_t)h * T_SEQ + row) * HD + d] = bv;
          else               Vt[((size_t)(h * HD + d)) * T_SEQ + row] = bv;
        } else {
          Cf[(size_t)row * NTOT + col] = v;
        }
      }
    }
  }
}

// ---------------- RoPE on Q and K (in place, bf16) ----------------
__global__ __launch_bounds__(256) void rope_k(unsigned short* __restrict__ Qb,
                                              unsigned short* __restrict__ Kb){
  const int j = threadIdx.x & 63;
  const int t = blockIdx.x * 4 + (threadIdx.x >> 6);
  const int h = blockIdx.y;
  const float fr = (float)t * __expf(-(float)j * (9.210340371976184f / 64.f));
  const float cs = cosf(fr), sn = sinf(fr);
  const size_t base = ((size_t)h * T_SEQ + t) * HD;
  {
    float x1 = bf2f(Qb[base + j]), x2 = bf2f(Qb[base + j + 64]);
    Qb[base + j]      = f2bf(x1 * cs - x2 * sn);
    Qb[base + j + 64] = f2bf(x2 * cs + x1 * sn);
  }
  {
    float x1 = bf2f(Kb[base + j]), x2 = bf2f(Kb[base + j + 64]);
    Kb[base + j]      = f2bf(x1 * cs - x2 * sn);
    Kb[base + j + 64] = f2bf(x2 * cs + x1 * sn);
  }
}

// ---------------- flash attention v7 ----------------
// Structure of v6 (grid 1024 LPT, 32 KB LDS, P overlay in dead lK region,
// stride-36 conflict-free P write) with the v6 BUG fixed:
// __launch_bounds__(256,4) capped the UNIFIED VGPR+AGPR file at 128/lane;
// o[2][8] accumulators = 64 AGPRs left only 64 arch VGPRs -> scratch spill
// (FETCH 399 MB, WRITE 65 MB of scratch traffic, 298 us). (256,2) gives the
// compiler a 256-reg budget: ~110 VGPR + 64 acc ~ 174 total -> no spill,
// 2-3 waves/SIMD by registers (LDS allows 5 blocks at 32768 B).
__global__ __launch_bounds__(256, 2) void attn_k(
    const unsigned short* __restrict__ Qb,   // [NH][T][HD]
    const unsigned short* __restrict__ Kb,   // [NH][T][HD]
    const unsigned short* __restrict__ Vt,   // [NH][HD][T]
    unsigned short* __restrict__ Yb)         // [T][HID]
{
  __shared__ __align__(16) unsigned char smem[32768];
  unsigned short* lK = (unsigned short*)smem;              // [64 keys][128 d] 16 KB
  unsigned short* lV = (unsigned short*)(smem + 16384);    // [128 d][64 keys] 16 KB
  float* lL = (float*)smem;                                // [64] (epilogue phase A)
  float* lO = (float*)smem;                                // [128][64] (epilogue phase C)

  const int tid  = threadIdx.x;
  const int w    = tid >> 6;
  const int rg   = w >> 1;
  const int kg   = w & 1;
  const int lane = tid & 63;
  const int qd   = lane >> 4;
  const int cc   = lane & 15;
  const int cx   = cc & 7;
  const int r8   = lane >> 3, c7 = lane & 7;

  const int b = blockIdx.x;                    // 1024 blocks
  const int h = (b & 7) + 8 * ((b >> 3) & 1);  // head; b&7 -> XCD pin
  const int tp = 63 - (b >> 4);                // tile, longest first (LPT)

  // staging source addressing (swizzle on fetch side; slot chunk c holds
  // global chunk c ^ (row&7))
  const int ce  = cc ^ qd;
  const int dlt = (ce & 4) ? -32 : 32;
  const unsigned short* gKbp = Kb + ((size_t)h * T_SEQ + w * 16 + qd) * HD + ce * 8;
  const int cV = c7 ^ r8;
  const unsigned short* gVbp = Vt + ((size_t)h * HD + w * 32 + r8) * T_SEQ + cV * 8;

  // per-wave P slice inside lK region: 4 KB each, stride 36 shorts
  unsigned short* lPw = lK + w * 2048;

  const f32x4 fzero = {0.f, 0.f, 0.f, 0.f};
  // 50*tanh(s*SCALE/50) ~= s*(A0 + A1*s^2 + A2*s^4)
  const float A0 = 0.0625f;
  const float A1 = -3.2552083e-8f;
  const float A2 = 2.0345052e-14f;

  const int qrow0 = tp * 64 + rg * 32;
  const int iters = tp + 1;

  // Q fragments: A-layout, rows qrow0 + mt*16 + cc, d = ks*32 + qd*8
  short8 qf[2][4];
#pragma unroll
  for (int mt = 0; mt < 2; ++mt)
#pragma unroll
    for (int ks = 0; ks < 4; ++ks)
      qf[mt][ks] = *(const short8*)(Qb + ((size_t)h * T_SEQ + qrow0 + mt * 16 + cc) * HD + ks * 32 + qd * 8);

  f32x4 o[2][8];
  float lsum[2][4];
#pragma unroll
  for (int mt = 0; mt < 2; ++mt){
#pragma unroll
    for (int dn = 0; dn < 8; ++dn) o[mt][dn] = fzero;
#pragma unroll
    for (int r = 0; r < 4; ++r) lsum[mt][r] = 0.f;
  }

#pragma unroll 1
  for (int it = 0; it < iters; ++it){
    const int k0 = it * 64;
    __syncthreads();   // B_a: prev iter's lK(P)/lV reads done
    {
      const unsigned short* gK = gKbp + (size_t)k0 * HD;
      const unsigned short* gV = gVbp + k0;
      unsigned short* dK = lK + w * 2048;
      unsigned short* dV = lV + w * 2048;
#pragma unroll
      for (int i = 0; i < 4; ++i)
        gll16(gK + (size_t)(i * 4) * HD + ((i & 1) ? dlt : 0), dK + i * 512);
#pragma unroll
      for (int i = 0; i < 4; ++i)
        gll16(gV + (size_t)i * 8 * T_SEQ, dV + i * 512);
    }
    __syncthreads();   // B_b: tiles visible

    // S = Q K^T : wave's keys = k0 + kg*32 + nt*16 + cc (nt=0..1)
    f32x4 S[2][2];
#pragma unroll
    for (int mt = 0; mt < 2; ++mt)
#pragma unroll
      for (int nt = 0; nt < 2; ++nt) S[mt][nt] = fzero;
#pragma unroll
    for (int nt = 0; nt < 2; ++nt){
      short8 kf[4];
#pragma unroll
      for (int ks = 0; ks < 4; ++ks)
        kf[ks] = *(const short8*)(lK + ((kg * 32 + nt * 16 + cc) * 16 + ((ks * 4 + qd) ^ cx)) * 8);
#pragma unroll
      for (int mt = 0; mt < 2; ++mt)
#pragma unroll
        for (int ks = 0; ks < 4; ++ks)
          S[mt][nt] = __builtin_amdgcn_mfma_f32_16x16x32_bf16(qf[mt][ks], kf[ks], S[mt][nt], 0, 0, 0);
    }

    // softcap (poly + med3 clamp) + exp, results in regs
    const bool domask = (it == iters - 1);
    unsigned short pv[2][2][4];
#pragma unroll
    for (int mt = 0; mt < 2; ++mt)
#pragma unroll
      for (int nt = 0; nt < 2; ++nt)
#pragma unroll
        for (int r = 0; r < 4; ++r){
          float s = S[mt][nt][r];
          float w2 = s * s;
          float t = fmaf(w2, A2, A1);
          t = fmaf(w2, t, A0);
          float a = __builtin_amdgcn_fmed3f(s * t, -50.f, 50.f);
          float p = __expf(a);
          if (domask){
            int col = k0 + kg * 32 + nt * 16 + cc;
            int row = qrow0 + mt * 16 + qd * 4 + r;
            if (col > row) p = 0.f;
          }
          unsigned u = __builtin_bit_cast(unsigned, p);
          lsum[mt][r] += __builtin_bit_cast(float, u & 0xffff0000u);
          pv[mt][nt][r] = (unsigned short)(u >> 16);
        }

    __syncthreads();   // B_c: all waves' kf reads done -> lK(P region) free

    // P write: stride 36 -> banks (8qd + cc>>1)%32, conflict-free
#pragma unroll
    for (int mt = 0; mt < 2; ++mt)
#pragma unroll
      for (int nt = 0; nt < 2; ++nt)
#pragma unroll
        for (int r = 0; r < 4; ++r)
          lPw[(mt * 16 + qd * 4 + r) * 36 + nt * 16 + cc] = pv[mt][nt][r];

    // P fragments (A-layout): row = mt*16+cc, keys qd*8..+7 (2x b64, 8B-aligned)
    short8 pf[2];
#pragma unroll
    for (int mt = 0; mt < 2; ++mt){
      const unsigned short* pb = lPw + (mt * 16 + cc) * 36 + qd * 8;
      union { short8 v; short4v hh[2]; } u;
      u.hh[0] = *(const short4v*)pb;
      u.hh[1] = *(const short4v*)(pb + 4);
      pf[mt] = u.v;
    }

    // O += P V : B-frag from lV, d-row = dn*16+cc, key chunk = kg*4+qd
#pragma unroll
    for (int dn = 0; dn < 8; ++dn){
      short8 vf = *(const short8*)(lV + ((dn * 16 + cc) * 8 + ((kg * 4 + qd) ^ cx)) * 8);
#pragma unroll
      for (int mt = 0; mt < 2; ++mt)
        o[mt][dn] = __builtin_amdgcn_mfma_f32_16x16x32_bf16(pf[mt], vf, o[mt][dn], 0, 0, 0);
    }
  }

  // ---- epilogue: reduce l over cc, merge kg partials (additive), store ----
  float lred[2][4];
#pragma unroll
  for (int mt = 0; mt < 2; ++mt)
#pragma unroll
    for (int r = 0; r < 4; ++r){
      float lb = lsum[mt][r];
      lb += __shfl_xor(lb, 1);
      lb += __shfl_xor(lb, 2);
      lb += __shfl_xor(lb, 4);
      lb += __shfl_xor(lb, 8);
      lred[mt][r] = lb;
    }

  __syncthreads();   // all K/V/P reads done; smem reusable
  // phase A: kg==1 publishes its l
  if (kg == 1 && cc == 0){
#pragma unroll
    for (int mt = 0; mt < 2; ++mt)
#pragma unroll
      for (int r = 0; r < 4; ++r)
        lL[rg * 32 + mt * 16 + qd * 4 + r] = lred[mt][r];
  }
  __syncthreads();
  // phase B: kg==0 computes inv from merged l
  float inv[2][4];
  if (kg == 0){
#pragma unroll
    for (int mt = 0; mt < 2; ++mt)
#pragma unroll
      for (int r = 0; r < 4; ++r)
        inv[mt][r] = __builtin_amdgcn_rcpf(lred[mt][r] + lL[rg * 32 + mt * 16 + qd * 4 + r]);
  }
  __syncthreads();
  // phase C: kg==1 publishes its O partial [128 d][64 rows]
  if (kg == 1){
#pragma unroll
    for (int mt = 0; mt < 2; ++mt)
#pragma unroll
      for (int dn = 0; dn < 8; ++dn)
        *(f32x4*)&lO[(dn * 16 + cc) * 64 + rg * 32 + mt * 16 + qd * 4] = o[mt][dn];
  }
  __syncthreads();
  // phase D: kg==0 merges, normalizes, stores
  if (kg == 0){
#pragma unroll
    for (int mt = 0; mt < 2; ++mt){
#pragma unroll
      for (int dn = 0; dn < 8; ++dn){
        f32x4 oo = o[mt][dn] + *(const f32x4*)&lO[(dn * 16 + cc) * 64 + rg * 32 + mt * 16 + qd * 4];
#pragma unroll
        for (int r = 0; r < 4; ++r){
          int row = qrow0 + mt * 16 + qd * 4 + r;
          Yb[(size_t)row * HID + h * HD + dn * 16 + cc] = f2bf(oo[r] * inv[mt][r]);
        }
      }
    }
  }
}

extern "C" void kernel_launch(void* const* d_in, const int* in_sizes, int n_in,
                              void* d_out, int out_size, void* d_ws, size_t ws_size,
                              hipStream_t stream) {
  const float* X  = (const float*)d_in[0];
  const float* Wq = (const float*)d_in[1];
  const float* Wk = (const float*)d_in[2];
  const float* Wv = (const float*)d_in[3];
  const float* Wo = (const float*)d_in[4];
  float* out = (float*)d_out;

  unsigned short* ws = (unsigned short*)d_ws;
  unsigned short* Xb = ws;                                   // [T][HID]        16 MiB
  unsigned short* Wt = ws + (size_t)8  * 1024 * 1024;        // [4*2048][2048]  32 MiB
  unsigned short* Qb = ws + (size_t)24 * 1024 * 1024;        // [NH][T][HD]     16 MiB
  unsigned short* Kb = ws + (size_t)32 * 1024 * 1024;        // [NH][T][HD]     16 MiB
  unsigned short* Vt = ws + (size_t)40 * 1024 * 1024;        // [NH][HD][T]     16 MiB
  unsigned short* Yb = Xb;                                   // reuse X region

  conv_x_k<<<8192, 256, 0, stream>>>(X, Xb);
  conv_wt_k<<<dim3(64, 64, 4), dim3(32, 8), 0, stream>>>(Wq, Wk, Wv, Wo, Wt);
  gemm_bt<0, 6144><<<dim3(48, 32), 256, 0, stream>>>(Xb, Wt, Qb, Kb, Vt, nullptr);
  rope_k<<<dim3(1024, NH), 256, 0, stream>>>(Qb, Kb);
  attn_k<<<dim3(1024), 256, 0, stream>>>(Qb, Kb, Vt, Yb);
  gemm_bt<1, 2048><<<dim3(16, 32), 256, 0, stream>>>(Yb, Wt + (size_t)6144 * 2048,
                                                     nullptr, nullptr, nullptr, out);
}